// Round 3
// baseline (624.728 us; speedup 1.0000x reference)
//
#include <hip/hip_runtime.h>

// ConvLSTM2D via MFMA implicit-GEMM. B=8,T=16,H=W=64,Cin=32,F=64,3x3 SAME.
// Round 3: fused 27-step K-loop with explicit rotating register prefetch
// (A dist-1 from LDS, B dist-2 from L2) to hide ds_read/L2 latency at the
// grid-capped 2 waves/SIMD occupancy. Bias folded into acc init.
//
// Per block: 8x8 pixel tile x 256 z-channels, 4 waves. Wave w owns N-tiles
// {w, w+4, w+8, w+12} -> gates i/f/c/o for channel w*16+col in the same
// lane/reg across the 4 tile-groups (no shuffle in epilogue).
// Weights prepacked to B-frag order [s(27)][nt(16)][lane(64)][8] (442 KB,
// L2-resident). h ping-pongs bf16 in ws; c-state fp32 in d_out (t=15
// epilogue replaces c with final h, same-lane RMW).

#define TSTEPS 16

typedef short bf16x8 __attribute__((ext_vector_type(8)));
typedef float f32x4 __attribute__((ext_vector_type(4)));

__device__ __forceinline__ float hsig(float x) {
    return fminf(fmaxf((x + 3.0f) * (1.0f / 6.0f), 0.0f), 1.0f);
}

__device__ __forceinline__ unsigned short f2bf(float f) {
    union { float f; unsigned int u; } v; v.f = f;
    unsigned int r = v.u + 0x7fffu + ((v.u >> 16) & 1u);  // RNE
    return (unsigned short)(r >> 16);
}

// ---- weight prepack: Wg(3,3,32,256), Ug(3,3,64,256) fp32 -> bf16 B-frags ----
// out[s][nt][lane][j]: B[k=(lane>>4)*8+j][n=nt*16+(lane&15)] for k-step s.
__global__ __launch_bounds__(256)
void prepack_w(const float* __restrict__ Wg, const float* __restrict__ Ug,
               unsigned short* __restrict__ out)
{
    int idx = blockIdx.x * 256 + threadIdx.x;   // 27*16*64 = 27648
    if (idx >= 27648) return;
    int lane = idx & 63;
    int nt   = (idx >> 6) & 15;
    int s    = idx >> 10;
    int col = lane & 15, quad = lane >> 4;
    int n = nt * 16 + col;
    int k0 = quad * 8;
    const float* src;
    if (s < 9) {
        src = Wg + ((size_t)s * 32 + k0) * 256 + n;
    } else {
        int ss = s - 9; int tap = ss >> 1; int half = ss & 1;
        src = Ug + ((size_t)tap * 64 + half * 32 + k0) * 256 + n;
    }
    unsigned short tmp[8];
    #pragma unroll
    for (int j = 0; j < 8; ++j) tmp[j] = f2bf(src[(size_t)j * 256]);
    *(uint4*)(out + (size_t)idx * 8) = *(uint4*)tmp;
}

// ---- one ConvLSTM step (NS = 9 for t==0, 27 otherwise) ----
template<int NS>
__global__ __launch_bounds__(256, 2)
void convlstm_step(const float* __restrict__ x,       // (B,T,64,64,32) fp32
                   const unsigned short* __restrict__ wpk,
                   const float* __restrict__ bias,    // (256)
                   const unsigned short* __restrict__ h_in, // bf16 (B,64,64,64)
                   float* __restrict__ c_st,          // fp32 (B,64,64,64) = d_out
                   unsigned short* __restrict__ h_out,// bf16 ping
                   int t, int is_last)
{
    constexpr bool HP = (NS == 27);
    __shared__ __align__(16) unsigned short xs_s[100 * 40];           // 8.0 KB
    __shared__ __align__(16) unsigned short hs_s[HP ? 100 * 72 : 8];  // 14.4 KB

    const int tid = threadIdx.x;
    const int gx0 = blockIdx.x * 8;
    const int gy0 = blockIdx.y * 8;
    const int b   = blockIdx.z;

    // ---- stage x halo (fp32 -> bf16) ----
    {
        const float* xt = x + (((size_t)b * TSTEPS + t) * (size_t)(64 * 64 * 32));
        #pragma unroll 4
        for (int idx = tid; idx < 100 * 8; idx += 256) {
            int pix = idx >> 3, q = idx & 7;
            int iy = pix / 10, ix = pix - iy * 10;
            int gy = gy0 + iy - 1, gx = gx0 + ix - 1;
            unsigned short o[4] = {0, 0, 0, 0};
            if ((unsigned)gy < 64u && (unsigned)gx < 64u) {
                float4 v = *(const float4*)(xt + ((size_t)(gy * 64 + gx) * 32) + q * 4);
                o[0] = f2bf(v.x); o[1] = f2bf(v.y); o[2] = f2bf(v.z); o[3] = f2bf(v.w);
            }
            *(ushort4*)(xs_s + pix * 40 + q * 4) = *(ushort4*)o;
        }
    }
    // ---- stage h halo (bf16 copy) ----
    if constexpr (HP) {
        const unsigned short* hb = h_in + ((size_t)b * (64 * 64 * 64));
        #pragma unroll 4
        for (int idx = tid; idx < 100 * 8; idx += 256) {
            int pix = idx >> 3, q = idx & 7;
            int iy = pix / 10, ix = pix - iy * 10;
            int gy = gy0 + iy - 1, gx = gx0 + ix - 1;
            uint4 v = make_uint4(0u, 0u, 0u, 0u);
            if ((unsigned)gy < 64u && (unsigned)gx < 64u)
                v = *(const uint4*)(hb + ((size_t)(gy * 64 + gx) * 64) + q * 8);
            *(uint4*)(hs_s + pix * 72 + q * 8) = v;
        }
    }
    __syncthreads();

    const int lane = tid & 63;
    const int w    = tid >> 6;
    const int quad = lane >> 4;
    const int m    = lane & 15;
    const int col  = lane & 15;
    const int ch   = w * 16 + col;   // output channel 0..63

    int xb[4], hb_[4];
    #pragma unroll
    for (int mt = 0; mt < 4; ++mt) {
        int p = mt * 16 + m;
        int py = p >> 3, px = p & 7;
        xb[mt]  = (py * 10 + px) * 40 + quad * 8;
        hb_[mt] = (py * 10 + px) * 72 + quad * 8;
    }

    // B-frag base: offset(s,g) = s*8192 + g*2048 elements from wb
    const unsigned short* wb = wpk + ((size_t)w * 64 + lane) * 8;

    // acc init = bias (all 4 rows of a C-tile share the channel's bias)
    f32x4 acc[4][4];   // [mt][gate]
    #pragma unroll
    for (int g = 0; g < 4; ++g) {
        float bv = bias[g * 64 + ch];
        f32x4 bi = (f32x4){bv, bv, bv, bv};
        #pragma unroll
        for (int mt = 0; mt < 4; ++mt) acc[mt][g] = bi;
    }

    auto loadA = [&](int s, bf16x8* dst) {
        if (s < 9) {
            int taplin = (s / 3) * 10 + (s % 3);
            #pragma unroll
            for (int mt = 0; mt < 4; ++mt)
                dst[mt] = *(const bf16x8*)(xs_s + xb[mt] + taplin * 40);
        } else {
            int ss = s - 9, tap = ss >> 1, half = ss & 1;
            int taplin = (tap / 3) * 10 + (tap % 3);
            #pragma unroll
            for (int mt = 0; mt < 4; ++mt)
                dst[mt] = *(const bf16x8*)(hs_s + hb_[mt] + taplin * 72 + half * 32);
        }
    };
    auto loadB = [&](int s, bf16x8* dst) {
        #pragma unroll
        for (int g = 0; g < 4; ++g)
            dst[g] = *(const bf16x8*)(wb + s * 8192 + g * 2048);
    };

    // ---- software-pipelined K-loop: A dist-1, B dist-2 ----
    bf16x8 aN[4], bp0[4], bp1[4];
    loadA(0, aN);
    loadB(0, bp0);
    if (NS > 1) loadB(1, bp1);

    #pragma unroll
    for (int s = 0; s < NS; ++s) {
        bf16x8 aC[4];
        #pragma unroll
        for (int mt = 0; mt < 4; ++mt) aC[mt] = aN[mt];
        if (s + 1 < NS) loadA(s + 1, aN);

        bf16x8 bC[4];
        #pragma unroll
        for (int g = 0; g < 4; ++g) bC[g] = (s & 1) ? bp1[g] : bp0[g];
        if (s + 2 < NS) loadB(s + 2, (s & 1) ? bp1 : bp0);

        #pragma unroll
        for (int g = 0; g < 4; ++g)
            #pragma unroll
            for (int mt = 0; mt < 4; ++mt)
                acc[mt][g] = __builtin_amdgcn_mfma_f32_16x16x32_bf16(aC[mt], bC[g], acc[mt][g], 0, 0, 0);
    }

    // ---- epilogue: gates + state update ----
    // C/D layout: col = lane&15 (channel), row = quad*4 + r (pixel)
    #pragma unroll
    for (int mt = 0; mt < 4; ++mt) {
        #pragma unroll
        for (int r = 0; r < 4; ++r) {
            int p = mt * 16 + quad * 4 + r;
            int py = p >> 3, px = p & 7;
            size_t gidx = (((size_t)b * 64 + (gy0 + py)) * 64 + (gx0 + px)) * 64 + ch;
            float zi = acc[mt][0][r];
            float zf = acc[mt][1][r];
            float zc = acc[mt][2][r];
            float zo = acc[mt][3][r];
            float c_prev = HP ? c_st[gidx] : 0.0f;
            float cn = hsig(zf) * c_prev + hsig(zi) * fmaxf(zc, 0.0f);
            float hn = hsig(zo) * fmaxf(cn, 0.0f);
            if (is_last) {
                c_st[gidx] = hn;            // d_out gets final h (fp32)
            } else {
                c_st[gidx] = cn;
                h_out[gidx] = f2bf(hn);
            }
        }
    }
}

extern "C" void kernel_launch(void* const* d_in, const int* in_sizes, int n_in,
                              void* d_out, int out_size, void* d_ws, size_t ws_size,
                              hipStream_t stream) {
    const float* x  = (const float*)d_in[0];
    const float* Wg = (const float*)d_in[1];
    const float* Ug = (const float*)d_in[2];
    const float* bs = (const float*)d_in[3];

    // ws layout: [packed weights 442368 B][h0 bf16 4 MB][h1 bf16 4 MB]
    unsigned short* wpk = (unsigned short*)d_ws;
    unsigned short* h0  = (unsigned short*)((char*)d_ws + 27 * 16 * 64 * 8 * 2);
    unsigned short* h1  = h0 + (size_t)8 * 64 * 64 * 64;
    float* cS = (float*)d_out;

    prepack_w<<<108, 256, 0, stream>>>(Wg, Ug, wpk);

    dim3 grid(8, 8, 8);
    dim3 block(256);
    for (int t = 0; t < TSTEPS; ++t) {
        const unsigned short* hin = (t == 0) ? h0 : ((t & 1) ? h0 : h1);
        unsigned short* hout = (t & 1) ? h1 : h0;
        if (t == 0) {
            convlstm_step<9><<<grid, block, 0, stream>>>(x, wpk, bs, hin, cS, hout, t, 0);
        } else {
            convlstm_step<27><<<grid, block, 0, stream>>>(x, wpk, bs, hin, cS, hout,
                                                          t, (t == TSTEPS - 1) ? 1 : 0);
        }
    }
}